// Round 2
// baseline (1462.129 us; speedup 1.0000x reference)
//
#include <hip/hip_runtime.h>

// Problem constants
static constexpr int SEQ = 50;
static constexpr int DIM = 32;

// ---------------------------------------------------------------------------
// Load one 32-float row (8x float4, coalesced across lanes = consecutive rows)
__device__ __forceinline__ void load_row(const float* __restrict__ p, float x[DIM]) {
    #pragma unroll
    for (int c = 0; c < 8; ++c) {
        float4 t = reinterpret_cast<const float4*>(p)[c];
        x[4*c+0] = t.x; x[4*c+1] = t.y; x[4*c+2] = t.z; x[4*c+3] = t.w;
    }
}

// In-place LayerNorm over 32 elements (pairwise trees for mean / mean-square)
__device__ __forceinline__ void ln_inplace(float x[DIM],
                                           const float* __restrict__ g,
                                           const float* __restrict__ bb) {
    float s[16], q[16];
    #pragma unroll
    for (int i = 0; i < 16; ++i) {
        s[i] = x[i] + x[i+16];
        q[i] = fmaf(x[i], x[i], x[i+16]*x[i+16]);
    }
    #pragma unroll
    for (int i = 0; i < 8; ++i) { s[i] += s[i+8]; q[i] += q[i+8]; }
    #pragma unroll
    for (int i = 0; i < 4; ++i) { s[i] += s[i+4]; q[i] += q[i+4]; }
    s[0] += s[2]; s[1] += s[3]; q[0] += q[2]; q[1] += q[3];
    const float mu  = (s[0] + s[1]) * (1.0f/32.0f);
    const float ms  = (q[0] + q[1]) * (1.0f/32.0f);
    const float var = ms - mu*mu;
    const float rs  = __builtin_amdgcn_rsqf(var + 1e-5f);
    #pragma unroll
    for (int d = 0; d < DIM; ++d) {
        const float t = (x[d] - mu) * rs;
        x[d] = fmaf(t, g[d], bb[d]);
    }
}

// y[c] = sum_d x[d]*W[c][d] + bias[c]  (W rows uniform -> s_loads)
__device__ __forceinline__ void gemv_reg(const float x[DIM],
                                         const float* __restrict__ W,
                                         const float* __restrict__ bias,
                                         float y[DIM]) {
    #pragma unroll
    for (int c = 0; c < DIM; ++c) {
        float acc = bias[c];
        #pragma unroll
        for (int d = 0; d < DIM; ++d) acc = fmaf(x[d], W[(c<<5)+d], acc);
        y[c] = acc;
    }
}

// Store one row to LDS with 16B-chunk rotation. For 8 consecutive lanes the
// byte addr mod 128 = ((cc+r)&7)*16 covers all 32 banks exactly once ->
// conflict-free ds_write_b128 (verified: SQ_LDS_BANK_CONFLICT == 0).
__device__ __forceinline__ void store_row_swz(float* __restrict__ buf, int row,
                                              const float y[DIM]) {
    #pragma unroll
    for (int cc = 0; cc < 8; ++cc) {
        const int phys = (cc + row) & 7;
        float4 t;
        t.x = y[4*cc+0]; t.y = y[4*cc+1]; t.z = y[4*cc+2]; t.w = y[4*cc+3];
        *reinterpret_cast<float4*>(&buf[(row << 5) + (phys << 2)]) = t;
    }
}

// One attention step for row j = j0 + u, where j0 % 8 == 0 so the chunk
// rotation (cc + j) & 7 == (cc + u) & 7 is COMPILE-TIME after unrolling:
// every LDS read is ds_read_b128 with an immediate offset, zero address VALU.
// bp = &sKV[0][j0*32] as float4*; V rows live at +400 float4 (6400 B).
__device__ __forceinline__ void attn_step(const float4* __restrict__ bp,
                                          const int u, const int j, const int r,
                                          const float q[DIM],
                                          float ctx[DIM], float l[4]) {
    float kj[DIM], vj[DIM];
    #pragma unroll
    for (int cc = 0; cc < 8; ++cc) {
        const int phys = (cc + u) & 7;               // constant after unroll
        const float4 tk = bp[(u << 3) + phys];       // imm <= 1008 B
        const float4 tv = bp[400 + (u << 3) + phys]; // imm <= 7408 B
        kj[4*cc+0]=tk.x; kj[4*cc+1]=tk.y; kj[4*cc+2]=tk.z; kj[4*cc+3]=tk.w;
        vj[4*cc+0]=tv.x; vj[4*cc+1]=tv.y; vj[4*cc+2]=tv.z; vj[4*cc+3]=tv.w;
    }
    float s[4] = {0.0f, 0.0f, 0.0f, 0.0f};
    #pragma unroll
    for (int d = 0; d < DIM; ++d) s[d>>3] = fmaf(q[d], kj[d], s[d>>3]);
    const bool um = (j <= r);                        // causal, diagonal open
    float p[4];
    #pragma unroll
    for (int h = 0; h < 4; ++h) {
        p[h] = um ? __builtin_amdgcn_exp2f(s[h]) : 0.0f;
        l[h] += p[h];
    }
    #pragma unroll
    for (int d = 0; d < DIM; ++d) ctx[d] = fmaf(p[d>>3], vj[d], ctx[d]);
}

__device__ __forceinline__ void epilogue_row(const float ctx_in[DIM], const float l[4],
                                             const float* __restrict__ Wo,
                                             const float* __restrict__ bo,
                                             const float* __restrict__ qres,
                                             float* __restrict__ outp) {
    float inv[4];
    #pragma unroll
    for (int h = 0; h < 4; ++h) inv[h] = __builtin_amdgcn_rcpf(l[h]);
    float ctx[DIM];
    #pragma unroll
    for (int d = 0; d < DIM; ++d) ctx[d] = ctx_in[d] * inv[d>>3];

    const float4* q4 = reinterpret_cast<const float4*>(qres);
    float4* o4 = reinterpret_cast<float4*>(outp);
    for (int cg = 0; cg < 8; ++cg) {          // rolled: uniform W index -> s_load
        float a0 = bo[cg*4+0], a1 = bo[cg*4+1], a2 = bo[cg*4+2], a3 = bo[cg*4+3];
        #pragma unroll
        for (int d = 0; d < DIM; ++d) {
            a0 = fmaf(ctx[d], Wo[((cg*4+0)<<5)+d], a0);
            a1 = fmaf(ctx[d], Wo[((cg*4+1)<<5)+d], a1);
            a2 = fmaf(ctx[d], Wo[((cg*4+2)<<5)+d], a2);
            a3 = fmaf(ctx[d], Wo[((cg*4+3)<<5)+d], a3);
        }
        const float4 qv = q4[cg];
        float4 ov;
        ov.x = a0 + qv.x; ov.y = a1 + qv.y; ov.z = a2 + qv.z; ov.w = a3 + qv.w;
        o4[cg] = ov;
    }
}

// One batch per 64-thread (single-wave) block; lane r owns q-row r (r < 50).
// LDS = K+V for ONE batch = 12.8 KB -> 12 blocks/CU. __launch_bounds__(64,4)
// caps VGPR at 128 so unroll-8 load hoisting can't cross the occupancy cliff.
__global__ __launch_bounds__(64, 4)
void mha_fused(const float* __restrict__ Q, const float* __restrict__ K,
               const float* __restrict__ V,
               const float* __restrict__ ln_g, const float* __restrict__ ln_b,
               const float* __restrict__ Wq, const float* __restrict__ bq,
               const float* __restrict__ Wk, const float* __restrict__ bk,
               const float* __restrict__ Wv, const float* __restrict__ bv,
               const float* __restrict__ Wo, const float* __restrict__ bo,
               float* __restrict__ Out, int nbatch)
{
    // K rows in sKV[0], V rows in sKV[1]: contiguous so V reads are the same
    // base VGPR + constant 6400 B immediate.
    __shared__ __align__(16) float sKV[2][SEQ * DIM];

    const int batch = (int)blockIdx.x;
    if (batch >= nbatch) return;
    const int r   = threadIdx.x;          // lane = query row
    const bool act = (r < SEQ);
    const size_t base = (size_t)batch * (SEQ * DIM);

    float q[DIM];
    if (act) {
        const size_t off = base + (size_t)r * DIM;
        // Issue all three row loads up front: one global latency, not three.
        float xk[DIM], xv[DIM], xq[DIM];
        load_row(K + off, xk);
        load_row(V + off, xv);
        load_row(Q + off, xq);

        float y[DIM];
        ln_inplace(xk, ln_g, ln_b);
        gemv_reg(xk, Wk, bk, y);
        store_row_swz(&sKV[0][0], r, y);
        ln_inplace(xv, ln_g, ln_b);
        gemv_reg(xv, Wv, bv, y);
        store_row_swz(&sKV[1][0], r, y);
        ln_inplace(xq, ln_g, ln_b);
        gemv_reg(xq, Wq, bq, q);
        // fold 1/sqrt(8) AND log2(e): softmax exp becomes a bare v_exp_f32
        const float sc = 0.35355339059327373f * 1.4426950408889634f;
        #pragma unroll
        for (int d = 0; d < DIM; ++d) q[d] *= sc;
    }
    __syncthreads();   // single-wave block: effectively a waitcnt, near-free

    if (act) {
        float ctx[DIM];
        #pragma unroll
        for (int d = 0; d < DIM; ++d) ctx[d] = 0.0f;
        float l[4] = {0.0f, 0.0f, 0.0f, 0.0f};

        const float4* kv4 = reinterpret_cast<const float4*>(&sKV[0][0]);

        // 48 rows in unrolled-by-8 blocks: u is compile-time inside each block
        for (int j0 = 0; j0 < 48; j0 += 8) {
            const float4* bp = kv4 + (j0 << 3);
            #pragma unroll
            for (int u = 0; u < 8; ++u)
                attn_step(bp, u, j0 + u, r, q, ctx, l);
        }
        // tail j = 48, 49: 48 % 8 == 0 so u = 0,1 give the correct swizzle
        {
            const float4* bp = kv4 + (48 << 3);
            attn_step(bp, 0, 48, r, q, ctx, l);
            attn_step(bp, 1, 49, r, q, ctx, l);
        }

        epilogue_row(ctx, l, Wo, bo, Q + base + (size_t)r * DIM,
                     Out + base + (size_t)r * DIM);
    }
}

extern "C" void kernel_launch(void* const* d_in, const int* in_sizes, int n_in,
                              void* d_out, int out_size, void* d_ws, size_t ws_size,
                              hipStream_t stream) {
    const float* Q    = (const float*)d_in[0];
    const float* K    = (const float*)d_in[1];
    const float* V    = (const float*)d_in[2];
    // d_in[3] = mask : causal triu(k=1); computed analytically, not read
    const float* ln_g = (const float*)d_in[4];
    const float* ln_b = (const float*)d_in[5];
    const float* Wq   = (const float*)d_in[6];
    const float* bq   = (const float*)d_in[7];
    const float* Wk   = (const float*)d_in[8];
    const float* bk   = (const float*)d_in[9];
    const float* Wv   = (const float*)d_in[10];
    const float* bv   = (const float*)d_in[11];
    const float* Wo   = (const float*)d_in[12];
    const float* bo   = (const float*)d_in[13];
    float* Out = (float*)d_out;

    const int nbatch = in_sizes[0] / (SEQ * DIM);   // 16384
    hipLaunchKernelGGL(mha_fused, dim3(nbatch), dim3(64), 0, stream,
                       Q, K, V, ln_g, ln_b, Wq, bq, Wk, bk, Wv, bv, Wo, bo,
                       Out, nbatch);
}

// Round 4
// 1128.216 us; speedup vs baseline: 1.2960x; 1.2960x over previous
//
#include <hip/hip_runtime.h>

// Problem constants
static constexpr int SEQ = 50;
static constexpr int DIM = 32;

// LDS layout: CHUNK-COLUMN-MAJOR.
//   chunk plane cc (cc = 0..7) holds the cc-th float4 of all 50 rows:
//     K chunk cc of row j at float index  cc*200 + j*4   (byte 800*cc + 16*j)
//     V chunk cc of row j at float index  1600 + cc*200 + j*4
// Writes (lane r = row, slot cc): bank group (8cc + 4r) mod 32 -> lanes 0..7
//   cover all 32 banks with disjoint 16B spans => conflict-free, NO padding.
// Reads (row j uniform across lanes): broadcast, base VGPR = 16*j, all 16
//   chunk offsets are compile-time immediates => zero per-iter address VALU.
static constexpr int KV_FLOATS = 2 * SEQ * DIM;   // 3200 floats = 12,800 B

// ---------------------------------------------------------------------------
// Load one 32-float row (8x float4, coalesced across lanes = consecutive rows)
__device__ __forceinline__ void load_row(const float* __restrict__ p, float x[DIM]) {
    #pragma unroll
    for (int c = 0; c < 8; ++c) {
        float4 t = reinterpret_cast<const float4*>(p)[c];
        x[4*c+0] = t.x; x[4*c+1] = t.y; x[4*c+2] = t.z; x[4*c+3] = t.w;
    }
}

// In-place LayerNorm over 32 elements (pairwise trees for mean / mean-square)
__device__ __forceinline__ void ln_inplace(float x[DIM],
                                           const float* __restrict__ g,
                                           const float* __restrict__ bb) {
    float s[16], q[16];
    #pragma unroll
    for (int i = 0; i < 16; ++i) {
        s[i] = x[i] + x[i+16];
        q[i] = fmaf(x[i], x[i], x[i+16]*x[i+16]);
    }
    #pragma unroll
    for (int i = 0; i < 8; ++i) { s[i] += s[i+8]; q[i] += q[i+8]; }
    #pragma unroll
    for (int i = 0; i < 4; ++i) { s[i] += s[i+4]; q[i] += q[i+4]; }
    s[0] += s[2]; s[1] += s[3]; q[0] += q[2]; q[1] += q[3];
    const float mu  = (s[0] + s[1]) * (1.0f/32.0f);
    const float ms  = (q[0] + q[1]) * (1.0f/32.0f);
    const float var = ms - mu*mu;
    const float rs  = __builtin_amdgcn_rsqf(var + 1e-5f);
    #pragma unroll
    for (int d = 0; d < DIM; ++d) {
        const float t = (x[d] - mu) * rs;
        x[d] = fmaf(t, g[d], bb[d]);
    }
}

// y[c] = sum_d x[d]*W[c][d] + bias[c]  (W rows uniform -> s_loads)
__device__ __forceinline__ void gemv_reg(const float x[DIM],
                                         const float* __restrict__ W,
                                         const float* __restrict__ bias,
                                         float y[DIM]) {
    #pragma unroll
    for (int c = 0; c < DIM; ++c) {
        float acc = bias[c];
        #pragma unroll
        for (int d = 0; d < DIM; ++d) acc = fmaf(x[d], W[(c<<5)+d], acc);
        y[c] = acc;
    }
}

// Store one row into the chunk-column-major layout. Static data indices,
// conflict-free banks (see header comment).
__device__ __forceinline__ void store_row_ccm(float* __restrict__ buf, int row,
                                              const float y[DIM]) {
    #pragma unroll
    for (int cc = 0; cc < 8; ++cc) {
        float4 t;
        t.x = y[4*cc+0]; t.y = y[4*cc+1]; t.z = y[4*cc+2]; t.w = y[4*cc+3];
        *reinterpret_cast<float4*>(&buf[cc*200 + (row<<2)]) = t;
    }
}

__device__ __forceinline__ void epilogue_row(const float ctx_in[DIM], const float l[4],
                                             const float* __restrict__ Wo,
                                             const float* __restrict__ bo,
                                             const float* __restrict__ qres,
                                             float* __restrict__ outp) {
    float inv[4];
    #pragma unroll
    for (int h = 0; h < 4; ++h) inv[h] = __builtin_amdgcn_rcpf(l[h]);
    float ctx[DIM];
    #pragma unroll
    for (int d = 0; d < DIM; ++d) ctx[d] = ctx_in[d] * inv[d>>3];

    const float4* q4 = reinterpret_cast<const float4*>(qres);
    float4* o4 = reinterpret_cast<float4*>(outp);
    for (int cg = 0; cg < 8; ++cg) {          // rolled: uniform W index -> s_load
        float a0 = bo[cg*4+0], a1 = bo[cg*4+1], a2 = bo[cg*4+2], a3 = bo[cg*4+3];
        #pragma unroll
        for (int d = 0; d < DIM; ++d) {
            a0 = fmaf(ctx[d], Wo[((cg*4+0)<<5)+d], a0);
            a1 = fmaf(ctx[d], Wo[((cg*4+1)<<5)+d], a1);
            a2 = fmaf(ctx[d], Wo[((cg*4+2)<<5)+d], a2);
            a3 = fmaf(ctx[d], Wo[((cg*4+3)<<5)+d], a3);
        }
        const float4 qv = q4[cg];
        float4 ov;
        ov.x = a0 + qv.x; ov.y = a1 + qv.y; ov.z = a2 + qv.z; ov.w = a3 + qv.w;
        o4[cg] = ov;
    }
}

// One batch per 64-thread (single-wave) block; lane r owns q-row r (r < 50).
// LDS = K+V for ONE batch = 12.8 KB -> 12 blocks/CU.
__global__ __launch_bounds__(64, 3)
void mha_fused(const float* __restrict__ Q, const float* __restrict__ K,
               const float* __restrict__ V,
               const float* __restrict__ ln_g, const float* __restrict__ ln_b,
               const float* __restrict__ Wq, const float* __restrict__ bq,
               const float* __restrict__ Wk, const float* __restrict__ bk,
               const float* __restrict__ Wv, const float* __restrict__ bv,
               const float* __restrict__ Wo, const float* __restrict__ bo,
               float* __restrict__ Out, int nbatch)
{
    __shared__ __align__(16) float sKV[KV_FLOATS];   // K planes then V planes

    const int batch = (int)blockIdx.x;
    if (batch >= nbatch) return;
    const int r   = threadIdx.x;          // lane = query row
    const bool act = (r < SEQ);
    const size_t base = (size_t)batch * (SEQ * DIM);

    float q[DIM];
    if (act) {
        const size_t off = base + (size_t)r * DIM;
        // Issue all three row loads up front: one global latency, not three.
        float xk[DIM], xv[DIM], xq[DIM];
        load_row(K + off, xk);
        load_row(V + off, xv);
        load_row(Q + off, xq);

        float y[DIM];
        ln_inplace(xk, ln_g, ln_b);
        gemv_reg(xk, Wk, bk, y);
        store_row_ccm(&sKV[0], r, y);
        ln_inplace(xv, ln_g, ln_b);
        gemv_reg(xv, Wv, bv, y);
        store_row_ccm(&sKV[SEQ * DIM], r, y);
        ln_inplace(xq, ln_g, ln_b);
        gemv_reg(xq, Wq, bq, q);
        // fold 1/sqrt(8) AND log2(e): softmax exp becomes a bare v_exp_f32
        const float sc = 0.35355339059327373f * 1.4426950408889634f;
        #pragma unroll
        for (int d = 0; d < DIM; ++d) q[d] *= sc;
    }
    __syncthreads();   // single-wave block: effectively a waitcnt, near-free

    if (act) {
        float ctx[DIM];
        #pragma unroll
        for (int d = 0; d < DIM; ++d) ctx[d] = 0.0f;
        float l[4] = {0.0f, 0.0f, 0.0f, 0.0f};

        #pragma unroll 2
        for (int j = 0; j < SEQ; ++j) {
            // Row j, uniform across lanes -> broadcast. Base VGPR = 16*j,
            // every chunk at a compile-time immediate offset.
            float kj[DIM], vj[DIM];
            #pragma unroll
            for (int cc = 0; cc < 8; ++cc) {
                const float4 tk = *reinterpret_cast<const float4*>(&sKV[cc*200 + (j<<2)]);
                kj[4*cc+0]=tk.x; kj[4*cc+1]=tk.y; kj[4*cc+2]=tk.z; kj[4*cc+3]=tk.w;
            }
            #pragma unroll
            for (int cc = 0; cc < 8; ++cc) {
                const float4 tv = *reinterpret_cast<const float4*>(&sKV[SEQ*DIM + cc*200 + (j<<2)]);
                vj[4*cc+0]=tv.x; vj[4*cc+1]=tv.y; vj[4*cc+2]=tv.z; vj[4*cc+3]=tv.w;
            }
            float s[4] = {0.0f, 0.0f, 0.0f, 0.0f};
            #pragma unroll
            for (int d = 0; d < DIM; ++d) s[d>>3] = fmaf(q[d], kj[d], s[d>>3]);

            const bool um = (j <= r);         // causal mask, diagonal unmasked
            float p[4];
            #pragma unroll
            for (int h = 0; h < 4; ++h) {
                p[h] = um ? __builtin_amdgcn_exp2f(s[h]) : 0.0f;
                l[h] += p[h];
            }
            #pragma unroll
            for (int d = 0; d < DIM; ++d) ctx[d] = fmaf(p[d>>3], vj[d], ctx[d]);
        }

        epilogue_row(ctx, l, Wo, bo, Q + base + (size_t)r * DIM,
                     Out + base + (size_t)r * DIM);
    }
}

extern "C" void kernel_launch(void* const* d_in, const int* in_sizes, int n_in,
                              void* d_out, int out_size, void* d_ws, size_t ws_size,
                              hipStream_t stream) {
    const float* Q    = (const float*)d_in[0];
    const float* K    = (const float*)d_in[1];
    const float* V    = (const float*)d_in[2];
    // d_in[3] = mask : causal triu(k=1); computed analytically, not read
    const float* ln_g = (const float*)d_in[4];
    const float* ln_b = (const float*)d_in[5];
    const float* Wq   = (const float*)d_in[6];
    const float* bq   = (const float*)d_in[7];
    const float* Wk   = (const float*)d_in[8];
    const float* bk   = (const float*)d_in[9];
    const float* Wv   = (const float*)d_in[10];
    const float* bv   = (const float*)d_in[11];
    const float* Wo   = (const float*)d_in[12];
    const float* bo   = (const float*)d_in[13];
    float* Out = (float*)d_out;

    const int nbatch = in_sizes[0] / (SEQ * DIM);   // 16384
    hipLaunchKernelGGL(mha_fused, dim3(nbatch), dim3(64), 0, stream,
                       Q, K, V, ln_g, ln_b, Wq, bq, Wk, bk, Wv, bv, Wo, bo,
                       Out, nbatch);
}

// Round 5
// 853.009 us; speedup vs baseline: 1.7141x; 1.3226x over previous
//
#include <hip/hip_runtime.h>

// Problem constants
static constexpr int SEQ = 50;
static constexpr int DIM = 32;

// Structure (round 5):
//  - one batch per 64-thread single-wave block; lane r owns q-row r (r < 50)
//  - K rows live in REGISTERS of their owner lane; score broadcast via
//    v_readlane (wave-uniform j) -> no LDS, no latency on the score path
//  - only V is staged in LDS (6.4 KB, chunk-column-major): V is consumed
//    ~100 cycles after its ds_reads issue (scores+exp in between), so the
//    LDS latency is hidden inside a single iteration
//  - LDS/block 6.4 KB -> 16 blocks/CU = 16 waves/CU (2x round-1 occupancy)
//  - output staged through the dead sV buffer and stored lane-striped:
//    every global_store_dwordx4 writes 1 KB contiguous = merge-proof
//    (fixes round-4's 16x HBM write amplification structurally)

// ---------------------------------------------------------------------------
__device__ __forceinline__ void load_row(const float* __restrict__ p, float x[DIM]) {
    #pragma unroll
    for (int c = 0; c < 8; ++c) {
        float4 t = reinterpret_cast<const float4*>(p)[c];
        x[4*c+0] = t.x; x[4*c+1] = t.y; x[4*c+2] = t.z; x[4*c+3] = t.w;
    }
}

// In-place LayerNorm over 32 elements (pairwise trees for mean / mean-square)
__device__ __forceinline__ void ln_inplace(float x[DIM],
                                           const float* __restrict__ g,
                                           const float* __restrict__ bb) {
    float s[16], q[16];
    #pragma unroll
    for (int i = 0; i < 16; ++i) {
        s[i] = x[i] + x[i+16];
        q[i] = fmaf(x[i], x[i], x[i+16]*x[i+16]);
    }
    #pragma unroll
    for (int i = 0; i < 8; ++i) { s[i] += s[i+8]; q[i] += q[i+8]; }
    #pragma unroll
    for (int i = 0; i < 4; ++i) { s[i] += s[i+4]; q[i] += q[i+4]; }
    s[0] += s[2]; s[1] += s[3]; q[0] += q[2]; q[1] += q[3];
    const float mu  = (s[0] + s[1]) * (1.0f/32.0f);
    const float ms  = (q[0] + q[1]) * (1.0f/32.0f);
    const float var = ms - mu*mu;
    const float rs  = __builtin_amdgcn_rsqf(var + 1e-5f);
    #pragma unroll
    for (int d = 0; d < DIM; ++d) {
        const float t = (x[d] - mu) * rs;
        x[d] = fmaf(t, g[d], bb[d]);
    }
}

// y[c] = sum_d x[d]*W[c][d] + bias[c]  (W rows wave-uniform -> s_loads)
__device__ __forceinline__ void gemv_reg(const float x[DIM],
                                         const float* __restrict__ W,
                                         const float* __restrict__ bias,
                                         float y[DIM]) {
    #pragma unroll
    for (int c = 0; c < DIM; ++c) {
        float acc = bias[c];
        #pragma unroll
        for (int d = 0; d < DIM; ++d) acc = fmaf(x[d], W[(c<<5)+d], acc);
        y[c] = acc;
    }
}

// Broadcast lane `l`'s value to all lanes (l is wave-uniform -> v_readlane)
__device__ __forceinline__ float lane_bcast(float v, int l) {
    return __int_as_float(__builtin_amdgcn_readlane(__float_as_int(v), l));
}

// One batch per single-wave block. VGPR target <= 128 (4 waves/EU).
__global__ __launch_bounds__(64, 4)
void mha_fused(const float* __restrict__ Q, const float* __restrict__ K,
               const float* __restrict__ V,
               const float* __restrict__ ln_g, const float* __restrict__ ln_b,
               const float* __restrict__ Wq, const float* __restrict__ bq,
               const float* __restrict__ Wk, const float* __restrict__ bk,
               const float* __restrict__ Wv, const float* __restrict__ bv,
               const float* __restrict__ Wo, const float* __restrict__ bo,
               float* __restrict__ Out, int nbatch)
{
    // V planes, chunk-column-major: chunk cc of row j at float cc*200 + 4j.
    // Writes (lane r, slot cc): banks (8cc+4r)%32, lanes 0..7 tile all 32
    // banks -> conflict-free. Reads (row j uniform): broadcast, base = 16j,
    // chunk offsets are compile-time immediates. Reused for output staging.
    __shared__ __align__(16) float sV[SEQ * DIM];   // 6400 B

    const int batch = (int)blockIdx.x;
    if (batch >= nbatch) return;
    const int r   = (int)threadIdx.x;     // lane = query row
    const bool act = (r < SEQ);
    const size_t base = (size_t)batch * (SEQ * DIM);

    float k[DIM], q[DIM];                 // persistent per-lane rows
    if (act) {
        const size_t off = base + (size_t)r * DIM;
        float x[DIM], y[DIM];
        // Sequential staging keeps peak register pressure ~100 VGPR
        load_row(K + off, x);
        ln_inplace(x, ln_g, ln_b);
        gemv_reg(x, Wk, bk, k);           // K row stays in registers
        load_row(V + off, x);
        ln_inplace(x, ln_g, ln_b);
        gemv_reg(x, Wv, bv, y);
        #pragma unroll
        for (int cc = 0; cc < 8; ++cc) {  // CCM store, conflict-free
            float4 t;
            t.x = y[4*cc+0]; t.y = y[4*cc+1]; t.z = y[4*cc+2]; t.w = y[4*cc+3];
            *reinterpret_cast<float4*>(&sV[cc*200 + (r<<2)]) = t;
        }
        load_row(Q + off, x);
        ln_inplace(x, ln_g, ln_b);
        gemv_reg(x, Wq, bq, q);
        // fold 1/sqrt(8) AND log2(e): softmax exp becomes a bare v_exp_f32
        const float sc = 0.35355339059327373f * 1.4426950408889634f;
        #pragma unroll
        for (int d = 0; d < DIM; ++d) q[d] *= sc;
    }
    __syncthreads();   // single-wave block: cheap; V visible to whole wave

    if (act) {
        float ctx[DIM];
        #pragma unroll
        for (int d = 0; d < DIM; ++d) ctx[d] = 0.0f;
        float l[4] = {0.0f, 0.0f, 0.0f, 0.0f};

        #pragma unroll 1   // keep register footprint small; V latency is
        for (int j = 0; j < SEQ; ++j) {   // hidden by the score/exp work below
            // Issue V row-j reads FIRST (consumed only after scores + exp)
            float vj[DIM];
            #pragma unroll
            for (int cc = 0; cc < 8; ++cc) {
                const float4 tv = *reinterpret_cast<const float4*>(&sV[cc*200 + (j<<2)]);
                vj[4*cc+0]=tv.x; vj[4*cc+1]=tv.y; vj[4*cc+2]=tv.z; vj[4*cc+3]=tv.w;
            }
            // Scores: K row j broadcast from lane j's registers (no memory).
            // Same fmaf order as round 1 -> bitwise-identical numerics.
            float s[4] = {0.0f, 0.0f, 0.0f, 0.0f};
            #pragma unroll
            for (int d = 0; d < DIM; ++d) {
                const float kd = lane_bcast(k[d], j);
                s[d>>3] = fmaf(q[d], kd, s[d>>3]);
            }
            const bool um = (j <= r);     // causal mask, diagonal unmasked
            float p[4];
            #pragma unroll
            for (int h = 0; h < 4; ++h) {
                p[h] = um ? __builtin_amdgcn_exp2f(s[h]) : 0.0f;
                l[h] += p[h];
            }
            #pragma unroll
            for (int d = 0; d < DIM; ++d) ctx[d] = fmaf(p[d>>3], vj[d], ctx[d]);
        }

        // Epilogue compute: normalize, Wo gemv, +residual; stage row in LDS
        // (sV is dead; same-wave LDS ops are ordered, so reuse is safe).
        float inv[4];
        #pragma unroll
        for (int h = 0; h < 4; ++h) inv[h] = __builtin_amdgcn_rcpf(l[h]);
        #pragma unroll
        for (int d = 0; d < DIM; ++d) ctx[d] *= inv[d>>3];

        const float4* q4 = reinterpret_cast<const float4*>(Q + base + (size_t)r * DIM);
        for (int cg = 0; cg < 8; ++cg) {  // rolled: uniform W index -> s_load
            float a0 = bo[cg*4+0], a1 = bo[cg*4+1], a2 = bo[cg*4+2], a3 = bo[cg*4+3];
            #pragma unroll
            for (int d = 0; d < DIM; ++d) {
                a0 = fmaf(ctx[d], Wo[((cg*4+0)<<5)+d], a0);
                a1 = fmaf(ctx[d], Wo[((cg*4+1)<<5)+d], a1);
                a2 = fmaf(ctx[d], Wo[((cg*4+2)<<5)+d], a2);
                a3 = fmaf(ctx[d], Wo[((cg*4+3)<<5)+d], a3);
            }
            const float4 qv = q4[cg];
            float4 ov;
            ov.x = a0 + qv.x; ov.y = a1 + qv.y; ov.z = a2 + qv.z; ov.w = a3 + qv.w;
            // linear row-major staging; write conflicts here are one-time
            // epilogue cost (~us chip-wide), irrelevant vs the j-loop
            *reinterpret_cast<float4*>(&sV[(r << 5) + (cg << 2)]) = ov;
        }
    }
    __syncthreads();

    // Coalesced output: 64 lanes stream 400 float4s; each store instruction
    // writes 1 KB of contiguous fully-dirty lines -> no write amplification.
    {
        float4* o4 = reinterpret_cast<float4*>(Out + base);
        const float4* s4 = reinterpret_cast<const float4*>(sV);
        #pragma unroll
        for (int i = 0; i < 7; ++i) {
            const int idx = (int)threadIdx.x + (i << 6);   // 0..447
            if (idx < (SEQ * DIM / 4)) o4[idx] = s4[idx];
        }
    }
}

extern "C" void kernel_launch(void* const* d_in, const int* in_sizes, int n_in,
                              void* d_out, int out_size, void* d_ws, size_t ws_size,
                              hipStream_t stream) {
    const float* Q    = (const float*)d_in[0];
    const float* K    = (const float*)d_in[1];
    const float* V    = (const float*)d_in[2];
    // d_in[3] = mask : causal triu(k=1); computed analytically, not read
    const float* ln_g = (const float*)d_in[4];
    const float* ln_b = (const float*)d_in[5];
    const float* Wq   = (const float*)d_in[6];
    const float* bq   = (const float*)d_in[7];
    const float* Wk   = (const float*)d_in[8];
    const float* bk   = (const float*)d_in[9];
    const float* Wv   = (const float*)d_in[10];
    const float* bv   = (const float*)d_in[11];
    const float* Wo   = (const float*)d_in[12];
    const float* bo   = (const float*)d_in[13];
    float* Out = (float*)d_out;

    const int nbatch = in_sizes[0] / (SEQ * DIM);   // 16384
    hipLaunchKernelGGL(mha_fused, dim3(nbatch), dim3(64), 0, stream,
                       Q, K, V, ln_g, ln_b, Wq, bq, Wk, bk, Wv, bv, Wo, bo,
                       Out, nbatch);
}